// Round 4
// baseline (1172.720 us; speedup 1.0000x reference)
//
#include <hip/hip_runtime.h>

#define N_NODES 150000
#define N_EDGES 600000
#define BATCH   1024
#define F_IN    78
#define F_HID   312
#define OUT_DIMW 128
#define SEQ_L   1000
#define VOCAB   26
#define EMB     128
#define NF      8
#define KS      8
#define CONV_WO 121     // EMB - KS + 1
#define CONV_FLAT 968   // NF * CONV_WO
#define SK      208     // VOCAB * KS
#define SLOPE   0.01f
#define KEY_NEGMAX ((int)0x80800000)   // fkey(-FLT_MAX): decodes to -3.4e38, never NaN

// order-preserving float<->int key for atomicMax on signed int
__device__ __forceinline__ int fkey(float v) {
  int i = __float_as_int(v);
  return i >= 0 ? i : (i ^ 0x7fffffff);
}
__device__ __forceinline__ float fdec(int k) {
  return __int_as_float(k >= 0 ? k : (k ^ 0x7fffffff));
}

// ---------------- init helpers ----------------
__global__ void k_zero_i(int* __restrict__ p, int n) {
  int i = blockIdx.x * blockDim.x + threadIdx.x;
  if (i < n) p[i] = 0;
}
__global__ void k_fill_i(int* __restrict__ p, int n, int val) {
  int i = blockIdx.x * blockDim.x + threadIdx.x;
  if (i < n) p[i] = val;
}

// ---------------- degree / norm ----------------
__global__ void k_deg(const int* __restrict__ dst, int* __restrict__ deg) {
  int e = blockIdx.x * blockDim.x + threadIdx.x;
  if (e < N_EDGES) atomicAdd(&deg[dst[e]], 1);
}

__global__ void k_dinv(const int* __restrict__ deg, float* __restrict__ dinv) {
  int i = blockIdx.x * blockDim.x + threadIdx.x;
  if (i < N_NODES) dinv[i] = rsqrtf((float)(deg[i] + 1));  // +1 self-loop
}

// exclusive prefix scan of deg[N_NODES] -> rowptr[N_NODES+1]; single block of 1024
__global__ __launch_bounds__(1024) void k_scan(const int* __restrict__ deg, int* __restrict__ rowptr) {
  __shared__ int part[1024];
  const int CH = (N_NODES + 1023) / 1024;   // 147
  int t = threadIdx.x;
  int base = t * CH;
  int mysum = 0;
  for (int i = 0; i < CH; i++) {
    int idx = base + i;
    if (idx < N_NODES) mysum += deg[idx];
  }
  part[t] = mysum;
  __syncthreads();
  for (int o = 1; o < 1024; o <<= 1) {
    int v = part[t];
    int add = (t >= o) ? part[t - o] : 0;
    __syncthreads();
    part[t] = v + add;
    __syncthreads();
  }
  int running = part[t] - mysum;            // exclusive offset for this chunk
  for (int i = 0; i < CH; i++) {
    int idx = base + i;
    if (idx < N_NODES) { rowptr[idx] = running; running += deg[idx]; }
  }
  if (t == 1023) rowptr[N_NODES] = part[1023];
}

// csr_src[rowptr[dst] + pos++] = src
__global__ void k_fillcsr(const int* __restrict__ src, const int* __restrict__ dst,
                          const int* __restrict__ rowptr, int* __restrict__ cnt,
                          int* __restrict__ csr) {
  int e = blockIdx.x * blockDim.x + threadIdx.x;
  if (e < N_EDGES) {
    int d = dst[e];
    int pos = rowptr[d] + atomicAdd(&cnt[d], 1);
    csr[pos] = src[e];
  }
}

// p[i] = dinv[row]*x[i]
__global__ void k_scale(const float* __restrict__ x, const float* __restrict__ dinv,
                        float* __restrict__ p) {
  int i = blockIdx.x * blockDim.x + threadIdx.x;
  if (i < N_NODES * F_IN) p[i] = dinv[i / F_IN] * x[i];
}

// pull: out[d] = dinv[d]^POW * (p[d] + sum_{s in in(d)} p[s]); one wave per node,
// 39 active lanes x float2 covering the 78-float row.
template<int POW>
__global__ __launch_bounds__(256) void k_pull(const int* __restrict__ rowptr,
                        const int* __restrict__ csr, const float* __restrict__ dinv,
                        const float* __restrict__ p, float* __restrict__ out) {
  int d = (int)((blockIdx.x * 256 + threadIdx.x) >> 6);
  int lane = threadIdx.x & 63;
  if (d >= N_NODES) return;
  int j0 = rowptr[d], j1 = rowptr[d + 1];
  bool act = lane < 39;
  float ax = 0.f, ay = 0.f, bx = 0.f, by = 0.f;
  if (act) {
    const float2* pd = (const float2*)(p + (size_t)d * F_IN);
    float2 v = pd[lane];
    ax = v.x; ay = v.y;
  }
  int j = j0;
  for (; j + 1 < j1; j += 2) {
    int s0 = csr[j], s1 = csr[j + 1];
    if (act) {
      const float2* p0 = (const float2*)(p + (size_t)s0 * F_IN);
      const float2* p1 = (const float2*)(p + (size_t)s1 * F_IN);
      float2 u = p0[lane], v = p1[lane];
      ax += u.x; ay += u.y; bx += v.x; by += v.y;
    }
  }
  if (j < j1) {
    int s0 = csr[j];
    if (act) {
      const float2* p0 = (const float2*)(p + (size_t)s0 * F_IN);
      float2 u = p0[lane];
      ax += u.x; ay += u.y;
    }
  }
  if (act) {
    float dv = dinv[d];
    float c = (POW == 2) ? dv * dv : dv;
    float2* od = (float2*)(out + (size_t)d * F_IN);
    od[lane] = make_float2(c * (ax + bx), c * (ay + by));
  }
}

// ---------------- generic fp32 GEMM: C = act(A[M,K] @ B[K,N] + bias) ----------------
// ACT: 0 none, 1 relu, 2 leaky(0.01)
template<int ACT>
__global__ __launch_bounds__(256) void k_gemm(const float* __restrict__ A, const float* __restrict__ B,
                       const float* __restrict__ bias, float* __restrict__ C,
                       int M, int N, int K, int ldc, int coff) {
  __shared__ float As[16][64];
  __shared__ float Bs[16][64];
  int bm = blockIdx.x * 64, bn = blockIdx.y * 64;
  int tid = threadIdx.x;
  int tx = tid & 15, ty = tid >> 4;
  float acc[4][4] = {};
  for (int k0 = 0; k0 < K; k0 += 16) {
    {
      int i = tid * 4;
      int m = i >> 4, k = i & 15;               // k in {0,4,8,12}
      const float* Ap = A + (size_t)(bm + m) * K + (k0 + k);
      bool mok = (bm + m) < M;
#pragma unroll
      for (int j = 0; j < 4; j++)
        As[k + j][m] = (mok && (k0 + k + j) < K) ? Ap[j] : 0.f;
    }
    {
      int i = tid * 4;
      int kr = i >> 6, n = i & 63;
      const float* Bp = B + (size_t)(k0 + kr) * N + (bn + n);
      bool kok = (k0 + kr) < K;
#pragma unroll
      for (int j = 0; j < 4; j++)
        Bs[kr][n + j] = (kok && (bn + n + j) < N) ? Bp[j] : 0.f;
    }
    __syncthreads();
#pragma unroll
    for (int kk = 0; kk < 16; kk++) {
      float4 a = *(const float4*)&As[kk][ty * 4];
      float4 b = *(const float4*)&Bs[kk][tx * 4];
      acc[0][0] += a.x * b.x; acc[0][1] += a.x * b.y; acc[0][2] += a.x * b.z; acc[0][3] += a.x * b.w;
      acc[1][0] += a.y * b.x; acc[1][1] += a.y * b.y; acc[1][2] += a.y * b.z; acc[1][3] += a.y * b.w;
      acc[2][0] += a.z * b.x; acc[2][1] += a.z * b.y; acc[2][2] += a.z * b.z; acc[2][3] += a.z * b.w;
      acc[3][0] += a.w * b.x; acc[3][1] += a.w * b.y; acc[3][2] += a.w * b.z; acc[3][3] += a.w * b.w;
    }
    __syncthreads();
  }
#pragma unroll
  for (int im = 0; im < 4; im++) {
    int m = bm + ty * 4 + im;
    if (m >= M) continue;
#pragma unroll
    for (int in = 0; in < 4; in++) {
      int n = bn + tx * 4 + in;
      if (n >= N) continue;
      float v = acc[im][in] + bias[n];
      if (ACT == 1) v = fmaxf(v, 0.f);
      if (ACT == 2) v = v > 0.f ? v : SLOPE * v;
      C[(size_t)m * ldc + coff + n] = v;
    }
  }
}

// ---------------- SGC linear + leaky + fused per-graph max ----------------
// graph(m) = (m*1024)/150000; a 64-row tile spans at most 2 graphs.
__global__ __launch_bounds__(256) void k_gemm_max(const float* __restrict__ A, const float* __restrict__ B,
                           const float* __restrict__ bias, int* __restrict__ gkeys) {
  const int M = N_NODES, Nn = F_HID, K = F_IN;
  __shared__ float As[16][64];
  __shared__ float Bs[16][64];
  __shared__ int red[2][64];
  int bm = blockIdx.x * 64, bn = blockIdx.y * 64;
  int tid = threadIdx.x;
  int tx = tid & 15, ty = tid >> 4;
  float acc[4][4] = {};
  for (int k0 = 0; k0 < K; k0 += 16) {
    {
      int i = tid * 4;
      int m = i >> 4, k = i & 15;
      const float* Ap = A + (size_t)(bm + m) * K + (k0 + k);
      bool mok = (bm + m) < M;
#pragma unroll
      for (int j = 0; j < 4; j++)
        As[k + j][m] = (mok && (k0 + k + j) < K) ? Ap[j] : 0.f;
    }
    {
      int i = tid * 4;
      int kr = i >> 6, n = i & 63;
      const float* Bp = B + (size_t)(k0 + kr) * Nn + (bn + n);
      bool kok = (k0 + kr) < K;
#pragma unroll
      for (int j = 0; j < 4; j++)
        Bs[kr][n + j] = (kok && (bn + n + j) < Nn) ? Bp[j] : 0.f;
    }
    __syncthreads();
#pragma unroll
    for (int kk = 0; kk < 16; kk++) {
      float4 a = *(const float4*)&As[kk][ty * 4];
      float4 b = *(const float4*)&Bs[kk][tx * 4];
      acc[0][0] += a.x * b.x; acc[0][1] += a.x * b.y; acc[0][2] += a.x * b.z; acc[0][3] += a.x * b.w;
      acc[1][0] += a.y * b.x; acc[1][1] += a.y * b.y; acc[1][2] += a.y * b.z; acc[1][3] += a.y * b.w;
      acc[2][0] += a.z * b.x; acc[2][1] += a.z * b.y; acc[2][2] += a.z * b.z; acc[2][3] += a.z * b.w;
      acc[3][0] += a.w * b.x; acc[3][1] += a.w * b.y; acc[3][2] += a.w * b.z; acc[3][3] += a.w * b.w;
    }
    __syncthreads();
  }
  // epilogue: leaky + per-(graph,col) max within block, then global atomicMax
  int g0 = (int)(((long long)bm * BATCH) / N_NODES);
  if (tid < 128) red[tid >> 6][tid & 63] = KEY_NEGMAX;
  __syncthreads();
#pragma unroll
  for (int im = 0; im < 4; im++) {
    int m = bm + ty * 4 + im;
    if (m >= M) continue;
    int flag = (int)(((long long)m * BATCH) / N_NODES) - g0;   // 0 or 1
#pragma unroll
    for (int in = 0; in < 4; in++) {
      int n = bn + tx * 4 + in;
      if (n >= Nn) continue;
      float v = acc[im][in] + bias[n];
      v = v > 0.f ? v : SLOPE * v;
      atomicMax(&red[flag][tx * 4 + in], fkey(v));
    }
  }
  __syncthreads();
  if (tid < 128) {
    int flag = tid >> 6, col = tid & 63;
    int n = bn + col;
    int g = g0 + flag;
    int key = red[flag][col];
    if (n < Nn && g < BATCH && key != KEY_NEGMAX)
      atomicMax(&gkeys[g * F_HID + n], key);
  }
}

__global__ void k_decode(const int* __restrict__ gkeys, float* __restrict__ g, int n) {
  int i = blockIdx.x * blockDim.x + threadIdx.x;
  if (i < n) g[i] = fdec(gkeys[i]);
}

// ---------------- S[b,f,v,k] = sum_{l: t[b,l]==v} conv_w[f,l,k] ----------------
__global__ __launch_bounds__(256) void k_sbuild(const int* __restrict__ target, const float* __restrict__ conv_w,
                         float* __restrict__ Sg) {
  __shared__ int tl[SEQ_L];
  __shared__ unsigned short order[SEQ_L];
  __shared__ int cnt[VOCAB];
  __shared__ int off[VOCAB + 1];
  __shared__ float Sl[VOCAB * 64];
  int b = blockIdx.x, tid = threadIdx.x;
  for (int l = tid; l < SEQ_L; l += 256) tl[l] = target[b * SEQ_L + l];
  if (tid < VOCAB) cnt[tid] = 0;
  __syncthreads();
  for (int l = tid; l < SEQ_L; l += 256) atomicAdd(&cnt[tl[l]], 1);
  __syncthreads();
  if (tid == 0) { off[0] = 0; for (int v = 0; v < VOCAB; v++) off[v + 1] = off[v] + cnt[v]; }
  __syncthreads();
  if (tid < VOCAB) cnt[tid] = 0;
  __syncthreads();
  for (int l = tid; l < SEQ_L; l += 256) {
    int v = tl[l];
    int p = atomicAdd(&cnt[v], 1);
    order[off[v] + p] = (unsigned short)l;
  }
  for (int i = tid; i < VOCAB * 64; i += 256) Sl[i] = 0.f;
  __syncthreads();
  int fk = tid & 63, q = tid >> 6;          // 64 (f,k) pairs x 4 l-slices
  int f = fk >> 3, k = fk & 7;
  const float* wp = conv_w + f * (SEQ_L * KS) + k;
  for (int v = 0; v < VOCAB; v++) {
    float acc = 0.f;
    for (int j = off[v] + q; j < off[v + 1]; j += 4) {
      int l = order[j];
      acc += wp[l * KS];
    }
    atomicAdd(&Sl[v * 64 + fk], acc);
  }
  __syncthreads();
  for (int i = tid; i < VOCAB * 64; i += 256) {
    int v = i >> 6, fk2 = i & 63;
    int ff = fk2 >> 3, kk = fk2 & 7;
    Sg[((size_t)b * NF + ff) * SK + v * KS + kk] = Sl[i];
  }
}

// ---------------- conv[b,f,w] = sum_{v,k} S[b,f,v,k]*emb[v,w+k] + conv_b[f] ----------------
__global__ __launch_bounds__(256) void k_conv(const float* __restrict__ Sg, const float* __restrict__ emb,
                       const float* __restrict__ conv_b, float* __restrict__ convo) {
  __shared__ float Asub[32][SK];       // 32 rows (b,f) x 208
  __shared__ float Etab[VOCAB * EMB];  // 26 x 128
  int r0 = blockIdx.x * 32;
  int tid = threadIdx.x;
  float* Af = &Asub[0][0];
  for (int i = tid; i < VOCAB * EMB; i += 256) Etab[i] = emb[i];
  for (int i = tid; i < 32 * SK; i += 256) Af[i] = Sg[(size_t)r0 * SK + i];
  __syncthreads();
  int w = tid & 127;
  int rg = tid >> 7;                   // 0..1 -> 16 rows each
  if (w < CONV_WO) {
    float acc[16] = {};
    for (int vk4 = 0; vk4 < SK; vk4 += 4) {
      int v0 = vk4 >> 3, k0 = vk4 & 7;  // 4|8 so all 4 share v0
      float e0 = Etab[v0 * EMB + w + k0];
      float e1 = Etab[v0 * EMB + w + k0 + 1];
      float e2 = Etab[v0 * EMB + w + k0 + 2];
      float e3 = Etab[v0 * EMB + w + k0 + 3];
#pragma unroll
      for (int r = 0; r < 16; r++) {
        float4 a4 = *(const float4*)&Asub[rg * 16 + r][vk4];
        acc[r] += a4.x * e0 + a4.y * e1 + a4.z * e2 + a4.w * e3;
      }
    }
#pragma unroll
    for (int r = 0; r < 16; r++) {
      int row = r0 + rg * 16 + r;      // row = b*8 + f
      convo[(size_t)row * CONV_WO + w] = acc[r] + conv_b[row & 7];
    }
  }
}

// ---------------- final 512 -> 1 layer: one wave per row ----------------
__global__ void k_out(const float* __restrict__ a2, const float* __restrict__ w,
                      const float* __restrict__ b, float* __restrict__ out) {
  int row = (blockIdx.x * blockDim.x + threadIdx.x) >> 6;
  int lane = threadIdx.x & 63;
  if (row >= BATCH) return;
  const float* ar = a2 + (size_t)row * 512;
  float s = 0.f;
  for (int j = lane; j < 512; j += 64) s += ar[j] * w[j];
  for (int o = 32; o > 0; o >>= 1) s += __shfl_down(s, o, 64);
  if (lane == 0) out[row] = s + b[0];
}

extern "C" void kernel_launch(void* const* d_in, const int* in_sizes, int n_in,
                              void* d_out, int out_size, void* d_ws, size_t ws_size,
                              hipStream_t stream) {
  const float* x      = (const float*)d_in[0];
  const float* sgc_w  = (const float*)d_in[1];
  const float* sgc_b  = (const float*)d_in[2];
  const float* fcg1_w = (const float*)d_in[3];
  const float* fcg1_b = (const float*)d_in[4];
  const float* emb    = (const float*)d_in[5];
  const float* conv_w = (const float*)d_in[6];
  const float* conv_b = (const float*)d_in[7];
  const float* fcxt_w = (const float*)d_in[8];
  const float* fcxt_b = (const float*)d_in[9];
  const float* fc1_w  = (const float*)d_in[10];
  const float* fc1_b  = (const float*)d_in[11];
  const float* fc2_w  = (const float*)d_in[12];
  const float* fc2_b  = (const float*)d_in[13];
  const float* out_w  = (const float*)d_in[14];
  const float* out_b  = (const float*)d_in[15];
  const int* edge     = (const int*)d_in[16];
  const int* target   = (const int*)d_in[18];
  float* out = (float*)d_out;

  char* ws = (char*)d_ws;
  size_t off = 0;
  auto take = [&](size_t bytes) {
    void* p = ws + off;
    off += (bytes + 255) & ~(size_t)255;
    return p;
  };
  int*   deg    = (int*)  take((size_t)N_NODES * 4);
  float* dinv   = (float*)take((size_t)N_NODES * 4);
  int*   rowptr = (int*)  take((size_t)(N_NODES + 1) * 4);
  int*   cnt    = (int*)  take((size_t)N_NODES * 4);
  int*   csr    = (int*)  take((size_t)N_EDGES * 4);
  float* hA     = (float*)take((size_t)N_NODES * F_IN * 4);   // 46.8 MB
  float* hB     = (float*)take((size_t)N_NODES * F_IN * 4);   // 46.8 MB
  int*   gkeys  = (int*)  take((size_t)BATCH * F_HID * 4);
  float* gbuf   = (float*)take((size_t)BATCH * F_HID * 4);
  float* Sg     = (float*)take((size_t)BATCH * NF * SK * 4);
  float* convo  = (float*)take((size_t)BATCH * NF * CONV_WO * 4);
  float* xc     = (float*)take((size_t)BATCH * 256 * 4);
  float* a1     = (float*)take((size_t)BATCH * 1024 * 4);
  float* a2     = (float*)take((size_t)BATCH * 512 * 4);
  // total ~120 MB (115 proven mapped in round 2/3)

  const int* esrc = edge;
  const int* edst = edge + N_EDGES;

  // CSR build (by destination)
  k_zero_i<<<(N_NODES + 255) / 256, 256, 0, stream>>>(deg, N_NODES);
  k_deg<<<(N_EDGES + 255) / 256, 256, 0, stream>>>(edst, deg);
  k_dinv<<<(N_NODES + 255) / 256, 256, 0, stream>>>(deg, dinv);
  k_scan<<<1, 1024, 0, stream>>>(deg, rowptr);
  k_zero_i<<<(N_NODES + 255) / 256, 256, 0, stream>>>(cnt, N_NODES);
  k_fillcsr<<<(N_EDGES + 255) / 256, 256, 0, stream>>>(esrc, edst, rowptr, cnt, csr);

  // SGConv via pull: p1 = dinv*x; p2 = dinv^2*(p1+sum); hB = dinv*(p2+sum)
  k_scale<<<(N_NODES * F_IN + 255) / 256, 256, 0, stream>>>(x, dinv, hA);
  k_pull<2><<<(N_NODES * 64 + 255) / 256, 256, 0, stream>>>(rowptr, csr, dinv, hA, hB);
  k_pull<1><<<(N_NODES * 64 + 255) / 256, 256, 0, stream>>>(rowptr, csr, dinv, hB, hA);

  // fused: h3 = leaky(hA @ sgc_w + sgc_b); gkeys = per-graph max (no h3 materialization)
  k_fill_i<<<(BATCH * F_HID + 255) / 256, 256, 0, stream>>>(gkeys, BATCH * F_HID, KEY_NEGMAX);
  dim3 g1((N_NODES + 63) / 64, (F_HID + 63) / 64);
  k_gemm_max<<<g1, 256, 0, stream>>>(hA, sgc_w, sgc_b, gkeys);
  k_decode<<<(BATCH * F_HID + 255) / 256, 256, 0, stream>>>(gkeys, gbuf, BATCH * F_HID);

  // fcg1 + leaky -> xc[:, 0:128]
  dim3 g2((BATCH + 63) / 64, (OUT_DIMW + 63) / 64);
  k_gemm<2><<<g2, 256, 0, stream>>>(gbuf, fcg1_w, fcg1_b, xc, BATCH, OUT_DIMW, F_HID, 256, 0);

  // protein branch
  k_sbuild<<<BATCH, 256, 0, stream>>>(target, conv_w, Sg);
  k_conv<<<(BATCH * NF) / 32, 256, 0, stream>>>(Sg, emb, conv_b, convo);
  // xt = conv_flat @ fcxt_w + fcxt_b -> xc[:, 128:256]
  k_gemm<0><<<g2, 256, 0, stream>>>(convo, fcxt_w, fcxt_b, xc, BATCH, OUT_DIMW, CONV_FLAT, 256, OUT_DIMW);

  // head
  dim3 g3((BATCH + 63) / 64, (1024 + 63) / 64);
  k_gemm<1><<<g3, 256, 0, stream>>>(xc, fc1_w, fc1_b, a1, BATCH, 1024, 256, 1024, 0);
  dim3 g4((BATCH + 63) / 64, (512 + 63) / 64);
  k_gemm<1><<<g4, 256, 0, stream>>>(a1, fc2_w, fc2_b, a2, BATCH, 512, 1024, 512, 0);
  k_out<<<(BATCH * 64) / 256, 256, 0, stream>>>(a2, out_w, out_b, out);
}

// Round 5
// 891.179 us; speedup vs baseline: 1.3159x; 1.3159x over previous
//
#include <hip/hip_runtime.h>

#define N_NODES 150000
#define N_EDGES 600000
#define BATCH   1024
#define F_IN    78
#define F_HID   312
#define OUT_DIMW 128
#define SEQ_L   1000
#define VOCAB   26
#define EMB     128
#define NF      8
#define KS      8
#define CONV_WO 121     // EMB - KS + 1
#define CONV_FLAT 968   // NF * CONV_WO
#define SK      208     // VOCAB * KS
#define SLOPE   0.01f
#define KEY_NEGMAX ((int)0x80800000)   // fkey(-FLT_MAX): decodes to -3.4e38, never NaN
#define SCAN_NBLK ((N_NODES + 255) / 256)   // 586

// order-preserving float<->int key for atomicMax on signed int
__device__ __forceinline__ int fkey(float v) {
  int i = __float_as_int(v);
  return i >= 0 ? i : (i ^ 0x7fffffff);
}
__device__ __forceinline__ float fdec(int k) {
  return __int_as_float(k >= 0 ? k : (k ^ 0x7fffffff));
}

// ---------------- init helpers ----------------
__global__ void k_zero_i(int* __restrict__ p, int n) {
  int i = blockIdx.x * blockDim.x + threadIdx.x;
  if (i < n) p[i] = 0;
}
__global__ void k_fill_i(int* __restrict__ p, int n, int val) {
  int i = blockIdx.x * blockDim.x + threadIdx.x;
  if (i < n) p[i] = val;
}

// ---------------- degree / norm ----------------
__global__ void k_deg(const int* __restrict__ dst, int* __restrict__ deg) {
  int e = blockIdx.x * blockDim.x + threadIdx.x;
  if (e < N_EDGES) atomicAdd(&deg[dst[e]], 1);
}

__global__ void k_dinv(const int* __restrict__ deg, float* __restrict__ dinv) {
  int i = blockIdx.x * blockDim.x + threadIdx.x;
  if (i < N_NODES) dinv[i] = rsqrtf((float)(deg[i] + 1));  // +1 self-loop
}

// ---------------- 3-stage parallel exclusive scan of deg -> rowptr ----------------
__global__ __launch_bounds__(256) void k_scan1(const int* __restrict__ deg, int* __restrict__ rowptr,
                                               int* __restrict__ bsum) {
  __shared__ int s[256];
  int tid = threadIdx.x;
  int i = blockIdx.x * 256 + tid;
  int v = (i < N_NODES) ? deg[i] : 0;
  s[tid] = v;
  __syncthreads();
  int x = v;
  for (int o = 1; o < 256; o <<= 1) {
    int t = (tid >= o) ? s[tid - o] : 0;
    __syncthreads();
    x += t; s[tid] = x;
    __syncthreads();
  }
  if (i < N_NODES) rowptr[i] = x - v;          // exclusive within block
  if (tid == 255) bsum[blockIdx.x] = x;        // block total
}

__global__ __launch_bounds__(1024) void k_scan2(int* __restrict__ bsum) {
  __shared__ int s[1024];
  int tid = threadIdx.x;
  int v = (tid < SCAN_NBLK) ? bsum[tid] : 0;
  s[tid] = v;
  __syncthreads();
  int x = v;
  for (int o = 1; o < 1024; o <<= 1) {
    int t = (tid >= o) ? s[tid - o] : 0;
    __syncthreads();
    x += t; s[tid] = x;
    __syncthreads();
  }
  if (tid < SCAN_NBLK) bsum[tid] = x - v;      // exclusive block prefix
}

__global__ __launch_bounds__(256) void k_scan3(int* __restrict__ rowptr, const int* __restrict__ bsum) {
  int i = blockIdx.x * 256 + threadIdx.x;
  if (i < N_NODES) rowptr[i] += bsum[blockIdx.x];
  if (i == 0) rowptr[N_NODES] = N_EDGES;       // total degree is exactly E
}

// csr_src[rowptr[dst] + pos++] = src
__global__ void k_fillcsr(const int* __restrict__ src, const int* __restrict__ dst,
                          const int* __restrict__ rowptr, int* __restrict__ cnt,
                          int* __restrict__ csr) {
  int e = blockIdx.x * blockDim.x + threadIdx.x;
  if (e < N_EDGES) {
    int d = dst[e];
    int pos = rowptr[d] + atomicAdd(&cnt[d], 1);
    csr[pos] = src[e];
  }
}

// p[i] = dinv[row]*x[i]
__global__ void k_scale(const float* __restrict__ x, const float* __restrict__ dinv,
                        float* __restrict__ p) {
  int i = blockIdx.x * blockDim.x + threadIdx.x;
  if (i < N_NODES * F_IN) p[i] = dinv[i / F_IN] * x[i];
}

// pull: out[d] = dinv[d]^POW * (p[d] + sum_{s in in(d)} p[s]); one wave per node,
// 39 active lanes x float2 covering the 78-float row.
template<int POW>
__global__ __launch_bounds__(256) void k_pull(const int* __restrict__ rowptr,
                        const int* __restrict__ csr, const float* __restrict__ dinv,
                        const float* __restrict__ p, float* __restrict__ out) {
  int d = (int)((blockIdx.x * 256 + threadIdx.x) >> 6);
  int lane = threadIdx.x & 63;
  if (d >= N_NODES) return;
  int j0 = rowptr[d], j1 = rowptr[d + 1];
  bool act = lane < 39;
  float ax = 0.f, ay = 0.f, bx = 0.f, by = 0.f;
  if (act) {
    const float2* pd = (const float2*)(p + (size_t)d * F_IN);
    float2 v = pd[lane];
    ax = v.x; ay = v.y;
  }
  int j = j0;
  for (; j + 1 < j1; j += 2) {
    int s0 = csr[j], s1 = csr[j + 1];
    if (act) {
      const float2* p0 = (const float2*)(p + (size_t)s0 * F_IN);
      const float2* p1 = (const float2*)(p + (size_t)s1 * F_IN);
      float2 u = p0[lane], v = p1[lane];
      ax += u.x; ay += u.y; bx += v.x; by += v.y;
    }
  }
  if (j < j1) {
    int s0 = csr[j];
    if (act) {
      const float2* p0 = (const float2*)(p + (size_t)s0 * F_IN);
      float2 u = p0[lane];
      ax += u.x; ay += u.y;
    }
  }
  if (act) {
    float dv = dinv[d];
    float c = (POW == 2) ? dv * dv : dv;
    float2* od = (float2*)(out + (size_t)d * F_IN);
    od[lane] = make_float2(c * (ax + bx), c * (ay + by));
  }
}

// ---------------- generic fp32 GEMM: C = act(A[M,K] @ B[K,N] + bias) ----------------
// ACT: 0 none, 1 relu, 2 leaky(0.01)
template<int ACT>
__global__ __launch_bounds__(256) void k_gemm(const float* __restrict__ A, const float* __restrict__ B,
                       const float* __restrict__ bias, float* __restrict__ C,
                       int M, int N, int K, int ldc, int coff) {
  __shared__ float As[16][64];
  __shared__ float Bs[16][64];
  int bm = blockIdx.x * 64, bn = blockIdx.y * 64;
  int tid = threadIdx.x;
  int tx = tid & 15, ty = tid >> 4;
  float acc[4][4] = {};
  for (int k0 = 0; k0 < K; k0 += 16) {
    {
      int i = tid * 4;
      int m = i >> 4, k = i & 15;               // k in {0,4,8,12}
      const float* Ap = A + (size_t)(bm + m) * K + (k0 + k);
      bool mok = (bm + m) < M;
#pragma unroll
      for (int j = 0; j < 4; j++)
        As[k + j][m] = (mok && (k0 + k + j) < K) ? Ap[j] : 0.f;
    }
    {
      int i = tid * 4;
      int kr = i >> 6, n = i & 63;
      const float* Bp = B + (size_t)(k0 + kr) * N + (bn + n);
      bool kok = (k0 + kr) < K;
#pragma unroll
      for (int j = 0; j < 4; j++)
        Bs[kr][n + j] = (kok && (bn + n + j) < N) ? Bp[j] : 0.f;
    }
    __syncthreads();
#pragma unroll
    for (int kk = 0; kk < 16; kk++) {
      float4 a = *(const float4*)&As[kk][ty * 4];
      float4 b = *(const float4*)&Bs[kk][tx * 4];
      acc[0][0] += a.x * b.x; acc[0][1] += a.x * b.y; acc[0][2] += a.x * b.z; acc[0][3] += a.x * b.w;
      acc[1][0] += a.y * b.x; acc[1][1] += a.y * b.y; acc[1][2] += a.y * b.z; acc[1][3] += a.y * b.w;
      acc[2][0] += a.z * b.x; acc[2][1] += a.z * b.y; acc[2][2] += a.z * b.z; acc[2][3] += a.z * b.w;
      acc[3][0] += a.w * b.x; acc[3][1] += a.w * b.y; acc[3][2] += a.w * b.z; acc[3][3] += a.w * b.w;
    }
    __syncthreads();
  }
#pragma unroll
  for (int im = 0; im < 4; im++) {
    int m = bm + ty * 4 + im;
    if (m >= M) continue;
#pragma unroll
    for (int in = 0; in < 4; in++) {
      int n = bn + tx * 4 + in;
      if (n >= N) continue;
      float v = acc[im][in] + bias[n];
      if (ACT == 1) v = fmaxf(v, 0.f);
      if (ACT == 2) v = v > 0.f ? v : SLOPE * v;
      C[(size_t)m * ldc + coff + n] = v;
    }
  }
}

// ---------------- SGC linear + leaky + fused per-graph max ----------------
// graph(m) = (m*1024)/150000; a 64-row tile spans at most 2 graphs.
__global__ __launch_bounds__(256) void k_gemm_max(const float* __restrict__ A, const float* __restrict__ B,
                           const float* __restrict__ bias, int* __restrict__ gkeys) {
  const int M = N_NODES, Nn = F_HID, K = F_IN;
  __shared__ float As[16][64];
  __shared__ float Bs[16][64];
  __shared__ int red[2][64];
  int bm = blockIdx.x * 64, bn = blockIdx.y * 64;
  int tid = threadIdx.x;
  int tx = tid & 15, ty = tid >> 4;
  float acc[4][4] = {};
  for (int k0 = 0; k0 < K; k0 += 16) {
    {
      int i = tid * 4;
      int m = i >> 4, k = i & 15;
      const float* Ap = A + (size_t)(bm + m) * K + (k0 + k);
      bool mok = (bm + m) < M;
#pragma unroll
      for (int j = 0; j < 4; j++)
        As[k + j][m] = (mok && (k0 + k + j) < K) ? Ap[j] : 0.f;
    }
    {
      int i = tid * 4;
      int kr = i >> 6, n = i & 63;
      const float* Bp = B + (size_t)(k0 + kr) * Nn + (bn + n);
      bool kok = (k0 + kr) < K;
#pragma unroll
      for (int j = 0; j < 4; j++)
        Bs[kr][n + j] = (kok && (bn + n + j) < Nn) ? Bp[j] : 0.f;
    }
    __syncthreads();
#pragma unroll
    for (int kk = 0; kk < 16; kk++) {
      float4 a = *(const float4*)&As[kk][ty * 4];
      float4 b = *(const float4*)&Bs[kk][tx * 4];
      acc[0][0] += a.x * b.x; acc[0][1] += a.x * b.y; acc[0][2] += a.x * b.z; acc[0][3] += a.x * b.w;
      acc[1][0] += a.y * b.x; acc[1][1] += a.y * b.y; acc[1][2] += a.y * b.z; acc[1][3] += a.y * b.w;
      acc[2][0] += a.z * b.x; acc[2][1] += a.z * b.y; acc[2][2] += a.z * b.z; acc[2][3] += a.z * b.w;
      acc[3][0] += a.w * b.x; acc[3][1] += a.w * b.y; acc[3][2] += a.w * b.z; acc[3][3] += a.w * b.w;
    }
    __syncthreads();
  }
  // epilogue: leaky + per-(graph,col) max within block, then global atomicMax
  int g0 = (int)(((long long)bm * BATCH) / N_NODES);
  if (tid < 128) red[tid >> 6][tid & 63] = KEY_NEGMAX;
  __syncthreads();
#pragma unroll
  for (int im = 0; im < 4; im++) {
    int m = bm + ty * 4 + im;
    if (m >= M) continue;
    int flag = (int)(((long long)m * BATCH) / N_NODES) - g0;   // 0 or 1
#pragma unroll
    for (int in = 0; in < 4; in++) {
      int n = bn + tx * 4 + in;
      if (n >= Nn) continue;
      float v = acc[im][in] + bias[n];
      v = v > 0.f ? v : SLOPE * v;
      atomicMax(&red[flag][tx * 4 + in], fkey(v));
    }
  }
  __syncthreads();
  if (tid < 128) {
    int flag = tid >> 6, col = tid & 63;
    int n = bn + col;
    int g = g0 + flag;
    int key = red[flag][col];
    if (n < Nn && g < BATCH && key != KEY_NEGMAX)
      atomicMax(&gkeys[g * F_HID + n], key);
  }
}

__global__ void k_decode(const int* __restrict__ gkeys, float* __restrict__ g, int n) {
  int i = blockIdx.x * blockDim.x + threadIdx.x;
  if (i < n) g[i] = fdec(gkeys[i]);
}

// ---------------- S[b,f,v,k] = sum_{l: t[b,l]==v} conv_w[f,l,k] ----------------
__global__ __launch_bounds__(256) void k_sbuild(const int* __restrict__ target, const float* __restrict__ conv_w,
                         float* __restrict__ Sg) {
  __shared__ int tl[SEQ_L];
  __shared__ unsigned short order[SEQ_L];
  __shared__ int cnt[VOCAB];
  __shared__ int off[VOCAB + 1];
  __shared__ float Sl[VOCAB * 64];
  int b = blockIdx.x, tid = threadIdx.x;
  for (int l = tid; l < SEQ_L; l += 256) tl[l] = target[b * SEQ_L + l];
  if (tid < VOCAB) cnt[tid] = 0;
  __syncthreads();
  for (int l = tid; l < SEQ_L; l += 256) atomicAdd(&cnt[tl[l]], 1);
  __syncthreads();
  if (tid == 0) { off[0] = 0; for (int v = 0; v < VOCAB; v++) off[v + 1] = off[v] + cnt[v]; }
  __syncthreads();
  if (tid < VOCAB) cnt[tid] = 0;
  __syncthreads();
  for (int l = tid; l < SEQ_L; l += 256) {
    int v = tl[l];
    int p = atomicAdd(&cnt[v], 1);
    order[off[v] + p] = (unsigned short)l;
  }
  for (int i = tid; i < VOCAB * 64; i += 256) Sl[i] = 0.f;
  __syncthreads();
  int fk = tid & 63, q = tid >> 6;          // 64 (f,k) pairs x 4 l-slices
  int f = fk >> 3, k = fk & 7;
  const float* wp = conv_w + f * (SEQ_L * KS) + k;
  for (int v = 0; v < VOCAB; v++) {
    float acc = 0.f;
    for (int j = off[v] + q; j < off[v + 1]; j += 4) {
      int l = order[j];
      acc += wp[l * KS];
    }
    atomicAdd(&Sl[v * 64 + fk], acc);
  }
  __syncthreads();
  for (int i = tid; i < VOCAB * 64; i += 256) {
    int v = i >> 6, fk2 = i & 63;
    int ff = fk2 >> 3, kk = fk2 & 7;
    Sg[((size_t)b * NF + ff) * SK + v * KS + kk] = Sl[i];
  }
}

// ---------------- conv[b,f,w] = sum_{v,k} S[b,f,v,k]*emb[v,w+k] + conv_b[f] ----------------
__global__ __launch_bounds__(256) void k_conv(const float* __restrict__ Sg, const float* __restrict__ emb,
                       const float* __restrict__ conv_b, float* __restrict__ convo) {
  __shared__ float Asub[32][SK];       // 32 rows (b,f) x 208
  __shared__ float Etab[VOCAB * EMB];  // 26 x 128
  int r0 = blockIdx.x * 32;
  int tid = threadIdx.x;
  float* Af = &Asub[0][0];
  for (int i = tid; i < VOCAB * EMB; i += 256) Etab[i] = emb[i];
  for (int i = tid; i < 32 * SK; i += 256) Af[i] = Sg[(size_t)r0 * SK + i];
  __syncthreads();
  int w = tid & 127;
  int rg = tid >> 7;                   // 0..1 -> 16 rows each
  if (w < CONV_WO) {
    float acc[16] = {};
    for (int vk4 = 0; vk4 < SK; vk4 += 4) {
      int v0 = vk4 >> 3, k0 = vk4 & 7;  // 4|8 so all 4 share v0
      float e0 = Etab[v0 * EMB + w + k0];
      float e1 = Etab[v0 * EMB + w + k0 + 1];
      float e2 = Etab[v0 * EMB + w + k0 + 2];
      float e3 = Etab[v0 * EMB + w + k0 + 3];
#pragma unroll
      for (int r = 0; r < 16; r++) {
        float4 a4 = *(const float4*)&Asub[rg * 16 + r][vk4];
        acc[r] += a4.x * e0 + a4.y * e1 + a4.z * e2 + a4.w * e3;
      }
    }
#pragma unroll
    for (int r = 0; r < 16; r++) {
      int row = r0 + rg * 16 + r;      // row = b*8 + f
      convo[(size_t)row * CONV_WO + w] = acc[r] + conv_b[row & 7];
    }
  }
}

// ---------------- final 512 -> 1 layer: one wave per row ----------------
__global__ void k_out(const float* __restrict__ a2, const float* __restrict__ w,
                      const float* __restrict__ b, float* __restrict__ out) {
  int row = (blockIdx.x * blockDim.x + threadIdx.x) >> 6;
  int lane = threadIdx.x & 63;
  if (row >= BATCH) return;
  const float* ar = a2 + (size_t)row * 512;
  float s = 0.f;
  for (int j = lane; j < 512; j += 64) s += ar[j] * w[j];
  for (int o = 32; o > 0; o >>= 1) s += __shfl_down(s, o, 64);
  if (lane == 0) out[row] = s + b[0];
}

extern "C" void kernel_launch(void* const* d_in, const int* in_sizes, int n_in,
                              void* d_out, int out_size, void* d_ws, size_t ws_size,
                              hipStream_t stream) {
  const float* x      = (const float*)d_in[0];
  const float* sgc_w  = (const float*)d_in[1];
  const float* sgc_b  = (const float*)d_in[2];
  const float* fcg1_w = (const float*)d_in[3];
  const float* fcg1_b = (const float*)d_in[4];
  const float* emb    = (const float*)d_in[5];
  const float* conv_w = (const float*)d_in[6];
  const float* conv_b = (const float*)d_in[7];
  const float* fcxt_w = (const float*)d_in[8];
  const float* fcxt_b = (const float*)d_in[9];
  const float* fc1_w  = (const float*)d_in[10];
  const float* fc1_b  = (const float*)d_in[11];
  const float* fc2_w  = (const float*)d_in[12];
  const float* fc2_b  = (const float*)d_in[13];
  const float* out_w  = (const float*)d_in[14];
  const float* out_b  = (const float*)d_in[15];
  const int* edge     = (const int*)d_in[16];
  const int* target   = (const int*)d_in[18];
  float* out = (float*)d_out;

  char* ws = (char*)d_ws;
  size_t off = 0;
  auto take = [&](size_t bytes) {
    void* p = ws + off;
    off += (bytes + 255) & ~(size_t)255;
    return p;
  };
  int*   deg    = (int*)  take((size_t)N_NODES * 4);
  float* dinv   = (float*)take((size_t)N_NODES * 4);
  int*   rowptr = (int*)  take((size_t)(N_NODES + 1) * 4);
  int*   bsum   = (int*)  take((size_t)SCAN_NBLK * 4);
  int*   cnt    = (int*)  take((size_t)N_NODES * 4);
  int*   csr    = (int*)  take((size_t)N_EDGES * 4);
  float* hA     = (float*)take((size_t)N_NODES * F_IN * 4);   // 46.8 MB
  float* hB     = (float*)take((size_t)N_NODES * F_IN * 4);   // 46.8 MB
  int*   gkeys  = (int*)  take((size_t)BATCH * F_HID * 4);
  float* gbuf   = (float*)take((size_t)BATCH * F_HID * 4);
  float* Sg     = (float*)take((size_t)BATCH * NF * SK * 4);
  float* convo  = (float*)take((size_t)BATCH * NF * CONV_WO * 4);
  float* xc     = (float*)take((size_t)BATCH * 256 * 4);
  float* a1     = (float*)take((size_t)BATCH * 1024 * 4);
  float* a2     = (float*)take((size_t)BATCH * 512 * 4);
  // total ~120 MB (proven mapped in rounds 3/4)

  const int* esrc = edge;
  const int* edst = edge + N_EDGES;

  // CSR build (by destination)
  k_zero_i<<<(N_NODES + 255) / 256, 256, 0, stream>>>(deg, N_NODES);
  k_deg<<<(N_EDGES + 255) / 256, 256, 0, stream>>>(edst, deg);
  k_dinv<<<(N_NODES + 255) / 256, 256, 0, stream>>>(deg, dinv);
  k_scan1<<<SCAN_NBLK, 256, 0, stream>>>(deg, rowptr, bsum);
  k_scan2<<<1, 1024, 0, stream>>>(bsum);
  k_scan3<<<SCAN_NBLK, 256, 0, stream>>>(rowptr, bsum);
  k_zero_i<<<(N_NODES + 255) / 256, 256, 0, stream>>>(cnt, N_NODES);
  k_fillcsr<<<(N_EDGES + 255) / 256, 256, 0, stream>>>(esrc, edst, rowptr, cnt, csr);

  // SGConv via pull: p1 = dinv*x; p2 = dinv^2*(p1+sum); hA = dinv*(p2+sum)
  k_scale<<<(N_NODES * F_IN + 255) / 256, 256, 0, stream>>>(x, dinv, hA);
  k_pull<2><<<(N_NODES * 64 + 255) / 256, 256, 0, stream>>>(rowptr, csr, dinv, hA, hB);
  k_pull<1><<<(N_NODES * 64 + 255) / 256, 256, 0, stream>>>(rowptr, csr, dinv, hB, hA);

  // fused: h3 = leaky(hA @ sgc_w + sgc_b); gkeys = per-graph max (no h3 materialization)
  k_fill_i<<<(BATCH * F_HID + 255) / 256, 256, 0, stream>>>(gkeys, BATCH * F_HID, KEY_NEGMAX);
  dim3 g1((N_NODES + 63) / 64, (F_HID + 63) / 64);
  k_gemm_max<<<g1, 256, 0, stream>>>(hA, sgc_w, sgc_b, gkeys);
  k_decode<<<(BATCH * F_HID + 255) / 256, 256, 0, stream>>>(gkeys, gbuf, BATCH * F_HID);

  // fcg1 + leaky -> xc[:, 0:128]
  dim3 g2((BATCH + 63) / 64, (OUT_DIMW + 63) / 64);
  k_gemm<2><<<g2, 256, 0, stream>>>(gbuf, fcg1_w, fcg1_b, xc, BATCH, OUT_DIMW, F_HID, 256, 0);

  // protein branch
  k_sbuild<<<BATCH, 256, 0, stream>>>(target, conv_w, Sg);
  k_conv<<<(BATCH * NF) / 32, 256, 0, stream>>>(Sg, emb, conv_b, convo);
  // xt = conv_flat @ fcxt_w + fcxt_b -> xc[:, 128:256]
  k_gemm<0><<<g2, 256, 0, stream>>>(convo, fcxt_w, fcxt_b, xc, BATCH, OUT_DIMW, CONV_FLAT, 256, OUT_DIMW);

  // head
  dim3 g3((BATCH + 63) / 64, (1024 + 63) / 64);
  k_gemm<1><<<g3, 256, 0, stream>>>(xc, fc1_w, fc1_b, a1, BATCH, 1024, 256, 1024, 0);
  dim3 g4((BATCH + 63) / 64, (512 + 63) / 64);
  k_gemm<1><<<g4, 256, 0, stream>>>(a1, fc2_w, fc2_b, a2, BATCH, 512, 1024, 512, 0);
  k_out<<<(BATCH * 64) / 256, 256, 0, stream>>>(a2, out_w, out_b, out);
}

// Round 6
// 853.823 us; speedup vs baseline: 1.3735x; 1.0438x over previous
//
#include <hip/hip_runtime.h>

#define N_NODES 150000
#define N_EDGES 600000
#define BATCH   1024
#define F_IN    78
#define F_HID   312
#define OUT_DIMW 128
#define SEQ_L   1000
#define VOCAB   26
#define EMB     128
#define NF      8
#define KS      8
#define CONV_WO 121     // EMB - KS + 1
#define CONV_FLAT 968   // NF * CONV_WO
#define SK      208     // VOCAB * KS
#define SLOPE   0.01f
#define KEY_NEGMAX ((int)0x80800000)   // fkey(-FLT_MAX): decodes to -3.4e38, never NaN
#define SCAN_NBLK ((N_NODES + 255) / 256)   // 586

// MFMA gemm_max geometry
#define KP   96          // K padded to 3x32
#define LDA  100         // LDS row stride (floats), 4-float aligned, 2-way banks
#define NT   20          // 20 n-tiles of 16 -> 320 >= 312
#define BSW_HALF (3 * NT * 64 * 8)   // 30720 shorts per (hi|lo) half

typedef __attribute__((ext_vector_type(8))) short bf8;   // 8 bf16 (4 VGPRs)
typedef __attribute__((ext_vector_type(4))) float f4;    // 4 fp32 acc

__device__ __forceinline__ short f2bf(float f) {         // RNE float->bf16 bits
  unsigned u = __float_as_uint(f);
  return (short)((u + 0x7fffu + ((u >> 16) & 1u)) >> 16);
}
__device__ __forceinline__ float bf2f(short h) {
  return __uint_as_float(((unsigned)(unsigned short)h) << 16);
}

// order-preserving float<->int key for atomicMax on signed int
__device__ __forceinline__ int fkey(float v) {
  int i = __float_as_int(v);
  return i >= 0 ? i : (i ^ 0x7fffffff);
}
__device__ __forceinline__ float fdec(int k) {
  return __int_as_float(k >= 0 ? k : (k ^ 0x7fffffff));
}

// ---------------- init helpers ----------------
__global__ void k_zero_i(int* __restrict__ p, int n) {
  int i = blockIdx.x * blockDim.x + threadIdx.x;
  if (i < n) p[i] = 0;
}
__global__ void k_fill_i(int* __restrict__ p, int n, int val) {
  int i = blockIdx.x * blockDim.x + threadIdx.x;
  if (i < n) p[i] = val;
}

// ---------------- degree / norm ----------------
__global__ void k_deg(const int* __restrict__ dst, int* __restrict__ deg) {
  int e = blockIdx.x * blockDim.x + threadIdx.x;
  if (e < N_EDGES) atomicAdd(&deg[dst[e]], 1);
}

__global__ void k_dinv(const int* __restrict__ deg, float* __restrict__ dinv) {
  int i = blockIdx.x * blockDim.x + threadIdx.x;
  if (i < N_NODES) dinv[i] = rsqrtf((float)(deg[i] + 1));  // +1 self-loop
}

// ---------------- 3-stage parallel exclusive scan of deg -> rowptr ----------------
__global__ __launch_bounds__(256) void k_scan1(const int* __restrict__ deg, int* __restrict__ rowptr,
                                               int* __restrict__ bsum) {
  __shared__ int s[256];
  int tid = threadIdx.x;
  int i = blockIdx.x * 256 + tid;
  int v = (i < N_NODES) ? deg[i] : 0;
  s[tid] = v;
  __syncthreads();
  int x = v;
  for (int o = 1; o < 256; o <<= 1) {
    int t = (tid >= o) ? s[tid - o] : 0;
    __syncthreads();
    x += t; s[tid] = x;
    __syncthreads();
  }
  if (i < N_NODES) rowptr[i] = x - v;          // exclusive within block
  if (tid == 255) bsum[blockIdx.x] = x;        // block total
}

__global__ __launch_bounds__(1024) void k_scan2(int* __restrict__ bsum) {
  __shared__ int s[1024];
  int tid = threadIdx.x;
  int v = (tid < SCAN_NBLK) ? bsum[tid] : 0;
  s[tid] = v;
  __syncthreads();
  int x = v;
  for (int o = 1; o < 1024; o <<= 1) {
    int t = (tid >= o) ? s[tid - o] : 0;
    __syncthreads();
    x += t; s[tid] = x;
    __syncthreads();
  }
  if (tid < SCAN_NBLK) bsum[tid] = x - v;      // exclusive block prefix
}

__global__ __launch_bounds__(256) void k_scan3(int* __restrict__ rowptr, const int* __restrict__ bsum) {
  int i = blockIdx.x * 256 + threadIdx.x;
  if (i < N_NODES) rowptr[i] += bsum[blockIdx.x];
  if (i == 0) rowptr[N_NODES] = N_EDGES;       // total degree is exactly E
}

// csr_src[rowptr[dst] + pos++] = src
__global__ void k_fillcsr(const int* __restrict__ src, const int* __restrict__ dst,
                          const int* __restrict__ rowptr, int* __restrict__ cnt,
                          int* __restrict__ csr) {
  int e = blockIdx.x * blockDim.x + threadIdx.x;
  if (e < N_EDGES) {
    int d = dst[e];
    int pos = rowptr[d] + atomicAdd(&cnt[d], 1);
    csr[pos] = src[e];
  }
}

// p[i] = dinv[row]*x[i]
__global__ void k_scale(const float* __restrict__ x, const float* __restrict__ dinv,
                        float* __restrict__ p) {
  int i = blockIdx.x * blockDim.x + threadIdx.x;
  if (i < N_NODES * F_IN) p[i] = dinv[i / F_IN] * x[i];
}

// pull: out[d] = dinv[d]^POW * (p[d] + sum_{s in in(d)} p[s]); one wave per node
template<int POW>
__global__ __launch_bounds__(256) void k_pull(const int* __restrict__ rowptr,
                        const int* __restrict__ csr, const float* __restrict__ dinv,
                        const float* __restrict__ p, float* __restrict__ out) {
  int d = (int)((blockIdx.x * 256 + threadIdx.x) >> 6);
  int lane = threadIdx.x & 63;
  if (d >= N_NODES) return;
  int j0 = rowptr[d], j1 = rowptr[d + 1];
  bool act = lane < 39;
  float ax = 0.f, ay = 0.f, bx = 0.f, by = 0.f;
  if (act) {
    const float2* pd = (const float2*)(p + (size_t)d * F_IN);
    float2 v = pd[lane];
    ax = v.x; ay = v.y;
  }
  int j = j0;
  for (; j + 1 < j1; j += 2) {
    int s0 = csr[j], s1 = csr[j + 1];
    if (act) {
      const float2* p0 = (const float2*)(p + (size_t)s0 * F_IN);
      const float2* p1 = (const float2*)(p + (size_t)s1 * F_IN);
      float2 u = p0[lane], v = p1[lane];
      ax += u.x; ay += u.y; bx += v.x; by += v.y;
    }
  }
  if (j < j1) {
    int s0 = csr[j];
    if (act) {
      const float2* p0 = (const float2*)(p + (size_t)s0 * F_IN);
      float2 u = p0[lane];
      ax += u.x; ay += u.y;
    }
  }
  if (act) {
    float dv = dinv[d];
    float c = (POW == 2) ? dv * dv : dv;
    float2* od = (float2*)(out + (size_t)d * F_IN);
    od[lane] = make_float2(c * (ax + bx), c * (ay + by));
  }
}

// ---------------- generic fp32 GEMM: C = act(A[M,K] @ B[K,N] + bias) ----------------
// ACT: 0 none, 1 relu, 2 leaky(0.01)
template<int ACT>
__global__ __launch_bounds__(256) void k_gemm(const float* __restrict__ A, const float* __restrict__ B,
                       const float* __restrict__ bias, float* __restrict__ C,
                       int M, int N, int K, int ldc, int coff) {
  __shared__ float As[16][64];
  __shared__ float Bs[16][64];
  int bm = blockIdx.x * 64, bn = blockIdx.y * 64;
  int tid = threadIdx.x;
  int tx = tid & 15, ty = tid >> 4;
  float acc[4][4] = {};
  for (int k0 = 0; k0 < K; k0 += 16) {
    {
      int i = tid * 4;
      int m = i >> 4, k = i & 15;               // k in {0,4,8,12}
      const float* Ap = A + (size_t)(bm + m) * K + (k0 + k);
      bool mok = (bm + m) < M;
#pragma unroll
      for (int j = 0; j < 4; j++)
        As[k + j][m] = (mok && (k0 + k + j) < K) ? Ap[j] : 0.f;
    }
    {
      int i = tid * 4;
      int kr = i >> 6, n = i & 63;
      const float* Bp = B + (size_t)(k0 + kr) * N + (bn + n);
      bool kok = (k0 + kr) < K;
#pragma unroll
      for (int j = 0; j < 4; j++)
        Bs[kr][n + j] = (kok && (bn + n + j) < N) ? Bp[j] : 0.f;
    }
    __syncthreads();
#pragma unroll
    for (int kk = 0; kk < 16; kk++) {
      float4 a = *(const float4*)&As[kk][ty * 4];
      float4 b = *(const float4*)&Bs[kk][tx * 4];
      acc[0][0] += a.x * b.x; acc[0][1] += a.x * b.y; acc[0][2] += a.x * b.z; acc[0][3] += a.x * b.w;
      acc[1][0] += a.y * b.x; acc[1][1] += a.y * b.y; acc[1][2] += a.y * b.z; acc[1][3] += a.y * b.w;
      acc[2][0] += a.z * b.x; acc[2][1] += a.z * b.y; acc[2][2] += a.z * b.z; acc[2][3] += a.z * b.w;
      acc[3][0] += a.w * b.x; acc[3][1] += a.w * b.y; acc[3][2] += a.w * b.z; acc[3][3] += a.w * b.w;
    }
    __syncthreads();
  }
#pragma unroll
  for (int im = 0; im < 4; im++) {
    int m = bm + ty * 4 + im;
    if (m >= M) continue;
#pragma unroll
    for (int in = 0; in < 4; in++) {
      int n = bn + tx * 4 + in;
      if (n >= N) continue;
      float v = acc[im][in] + bias[n];
      if (ACT == 1) v = fmaxf(v, 0.f);
      if (ACT == 2) v = v > 0.f ? v : SLOPE * v;
      C[(size_t)m * ldc + coff + n] = v;
    }
  }
}

// ---------------- B pre-split + pre-swizzle for MFMA fragments ----------------
// Bsw[hi half | lo half]; idx = ((ksi*NT + nt)*64 + lane)*8 + j
// maps to B[k = ksi*32 + (lane>>4)*8 + j][n = nt*16 + (lane&15)]
__global__ void k_bprep(const float* __restrict__ B, short* __restrict__ Bsw) {
  int i = blockIdx.x * 256 + threadIdx.x;
  if (i >= BSW_HALF) return;
  int j = i & 7;
  int lane = (i >> 3) & 63;
  int rest = i >> 9;
  int nt = rest % NT, ksi = rest / NT;
  int n = nt * 16 + (lane & 15);
  int k = ksi * 32 + (lane >> 4) * 8 + j;
  float v = (k < F_IN && n < F_HID) ? B[k * F_HID + n] : 0.f;
  short h = f2bf(v);
  Bsw[i] = h;
  Bsw[BSW_HALF + i] = f2bf(v - bf2f(h));
}

// ---------------- split-bf16 MFMA SGC-linear + leaky + fused per-graph max ----------------
// 64 rows per block, full N=312 (padded 320). a*b ~= ahi*bhi + ahi*blo + alo*bhi.
__global__ __launch_bounds__(256) void k_gemm_max(const float* __restrict__ A,
                           const short* __restrict__ Bsw,
                           const float* __restrict__ bias, int* __restrict__ gkeys) {
  __shared__ float As[64 * LDA];      // 25.6 KB fp32 A-tile, zero-padded K to 96
  __shared__ int red[2 * F_HID];      // per-(graph,col) max
  int tid = threadIdx.x;
  int m0 = blockIdx.x * 64;

  // stage A-tile (coalesced along k runs)
  for (int i = tid; i < 64 * KP; i += 256) {
    int m = i / KP, k = i - m * KP;
    int gm = m0 + m;
    float v = (k < F_IN && gm < N_NODES) ? A[(size_t)gm * F_IN + k] : 0.f;
    As[m * LDA + k] = v;
  }
  for (int i = tid; i < 2 * F_HID; i += 256) red[i] = KEY_NEGMAX;
  __syncthreads();

  int w = tid >> 6, lane = tid & 63;
  int mrow = lane & 15, quad = lane >> 4;

  f4 acc[NT];
#pragma unroll
  for (int nt = 0; nt < NT; nt++) acc[nt] = (f4)0.f;

#pragma unroll
  for (int ksi = 0; ksi < 3; ksi++) {
    // A fragment from LDS: row = w*16+mrow, k = ksi*32 + quad*8 .. +7; split hi/lo
    const float* ap = &As[(w * 16 + mrow) * LDA + ksi * 32 + quad * 8];
    float4 a0 = *(const float4*)ap;
    float4 a1 = *(const float4*)(ap + 4);
    float av[8] = {a0.x, a0.y, a0.z, a0.w, a1.x, a1.y, a1.z, a1.w};
    bf8 ahi, alo;
#pragma unroll
    for (int j = 0; j < 8; j++) {
      short h = f2bf(av[j]);
      ahi[j] = h;
      alo[j] = f2bf(av[j] - bf2f(h));
    }
    const short* bph = Bsw + ((size_t)ksi * NT * 64 + lane) * 8;
#pragma unroll
    for (int nt = 0; nt < NT; nt++) {
      bf8 bhi = *(const bf8*)(bph + nt * 512);
      bf8 blo = *(const bf8*)(bph + BSW_HALF + nt * 512);
      acc[nt] = __builtin_amdgcn_mfma_f32_16x16x32_bf16(ahi, bhi, acc[nt], 0, 0, 0);
      acc[nt] = __builtin_amdgcn_mfma_f32_16x16x32_bf16(ahi, blo, acc[nt], 0, 0, 0);
      acc[nt] = __builtin_amdgcn_mfma_f32_16x16x32_bf16(alo, bhi, acc[nt], 0, 0, 0);
    }
  }

  // epilogue: C/D layout col=lane&15, row=quad*4+reg (verified m89/m91)
  int g0 = (int)(((long long)m0 * BATCH) / N_NODES);
#pragma unroll
  for (int nt = 0; nt < NT; nt++) {
    int n = nt * 16 + mrow;
    if (n >= F_HID) continue;
    float bn = bias[n];
#pragma unroll
    for (int r = 0; r < 4; r++) {
      int m = m0 + w * 16 + quad * 4 + r;
      if (m >= N_NODES) continue;
      int flag = (int)(((long long)m * BATCH) / N_NODES) - g0;   // 0 or 1
      float v = acc[nt][r] + bn;
      v = v > 0.f ? v : SLOPE * v;
      atomicMax(&red[flag * F_HID + n], fkey(v));
    }
  }
  __syncthreads();
  for (int i = tid; i < 2 * F_HID; i += 256) {
    int flag = i / F_HID, n = i - flag * F_HID;
    int g = g0 + flag;
    int key = red[i];
    if (g < BATCH && key != KEY_NEGMAX)
      atomicMax(&gkeys[g * F_HID + n], key);
  }
}

__global__ void k_decode(const int* __restrict__ gkeys, float* __restrict__ g, int n) {
  int i = blockIdx.x * blockDim.x + threadIdx.x;
  if (i < n) g[i] = fdec(gkeys[i]);
}

// ---------------- S[b,f,v,k] = sum_{l: t[b,l]==v} conv_w[f,l,k] ----------------
__global__ __launch_bounds__(256) void k_sbuild(const int* __restrict__ target, const float* __restrict__ conv_w,
                         float* __restrict__ Sg) {
  __shared__ int tl[SEQ_L];
  __shared__ unsigned short order[SEQ_L];
  __shared__ int cnt[VOCAB];
  __shared__ int off[VOCAB + 1];
  __shared__ float Sl[VOCAB * 64];
  int b = blockIdx.x, tid = threadIdx.x;
  for (int l = tid; l < SEQ_L; l += 256) tl[l] = target[b * SEQ_L + l];
  if (tid < VOCAB) cnt[tid] = 0;
  __syncthreads();
  for (int l = tid; l < SEQ_L; l += 256) atomicAdd(&cnt[tl[l]], 1);
  __syncthreads();
  if (tid == 0) { off[0] = 0; for (int v = 0; v < VOCAB; v++) off[v + 1] = off[v] + cnt[v]; }
  __syncthreads();
  if (tid < VOCAB) cnt[tid] = 0;
  __syncthreads();
  for (int l = tid; l < SEQ_L; l += 256) {
    int v = tl[l];
    int p = atomicAdd(&cnt[v], 1);
    order[off[v] + p] = (unsigned short)l;
  }
  for (int i = tid; i < VOCAB * 64; i += 256) Sl[i] = 0.f;
  __syncthreads();
  int fk = tid & 63, q = tid >> 6;          // 64 (f,k) pairs x 4 l-slices
  int f = fk >> 3, k = fk & 7;
  const float* wp = conv_w + f * (SEQ_L * KS) + k;
  for (int v = 0; v < VOCAB; v++) {
    float acc = 0.f;
    for (int j = off[v] + q; j < off[v + 1]; j += 4) {
      int l = order[j];
      acc += wp[l * KS];
    }
    atomicAdd(&Sl[v * 64 + fk], acc);
  }
  __syncthreads();
  for (int i = tid; i < VOCAB * 64; i += 256) {
    int v = i >> 6, fk2 = i & 63;
    int ff = fk2 >> 3, kk = fk2 & 7;
    Sg[((size_t)b * NF + ff) * SK + v * KS + kk] = Sl[i];
  }
}

// ---------------- conv[b,f,w] = sum_{v,k} S[b,f,v,k]*emb[v,w+k] + conv_b[f] ----------------
__global__ __launch_bounds__(256) void k_conv(const float* __restrict__ Sg, const float* __restrict__ emb,
                       const float* __restrict__ conv_b, float* __restrict__ convo) {
  __shared__ float Asub[32][SK];       // 32 rows (b,f) x 208
  __shared__ float Etab[VOCAB * EMB];  // 26 x 128
  int r0 = blockIdx.x * 32;
  int tid = threadIdx.x;
  float* Af = &Asub[0][0];
  for (int i = tid; i < VOCAB * EMB; i += 256) Etab[i] = emb[i];
  for (int i = tid; i < 32 * SK; i += 256) Af[i] = Sg[(size_t)r0 * SK + i];
  __syncthreads();
  int w = tid & 127;
  int rg = tid >> 7;                   // 0..1 -> 16 rows each
  if (w < CONV_WO) {
    float acc[16] = {};
    for (int vk4 = 0; vk4 < SK; vk4 += 4) {
      int v0 = vk4 >> 3, k0 = vk4 & 7;  // 4|8 so all 4 share v0
      float e0 = Etab[v0 * EMB + w + k0];
      float e1 = Etab[v0 * EMB + w + k0 + 1];
      float e2 = Etab[v0 * EMB + w + k0 + 2];
      float e3 = Etab[v0 * EMB + w + k0 + 3];
#pragma unroll
      for (int r = 0; r < 16; r++) {
        float4 a4 = *(const float4*)&Asub[rg * 16 + r][vk4];
        acc[r] += a4.x * e0 + a4.y * e1 + a4.z * e2 + a4.w * e3;
      }
    }
#pragma unroll
    for (int r = 0; r < 16; r++) {
      int row = r0 + rg * 16 + r;      // row = b*8 + f
      convo[(size_t)row * CONV_WO + w] = acc[r] + conv_b[row & 7];
    }
  }
}

// ---------------- final 512 -> 1 layer: one wave per row ----------------
__global__ void k_out(const float* __restrict__ a2, const float* __restrict__ w,
                      const float* __restrict__ b, float* __restrict__ out) {
  int row = (blockIdx.x * blockDim.x + threadIdx.x) >> 6;
  int lane = threadIdx.x & 63;
  if (row >= BATCH) return;
  const float* ar = a2 + (size_t)row * 512;
  float s = 0.f;
  for (int j = lane; j < 512; j += 64) s += ar[j] * w[j];
  for (int o = 32; o > 0; o >>= 1) s += __shfl_down(s, o, 64);
  if (lane == 0) out[row] = s + b[0];
}

extern "C" void kernel_launch(void* const* d_in, const int* in_sizes, int n_in,
                              void* d_out, int out_size, void* d_ws, size_t ws_size,
                              hipStream_t stream) {
  const float* x      = (const float*)d_in[0];
  const float* sgc_w  = (const float*)d_in[1];
  const float* sgc_b  = (const float*)d_in[2];
  const float* fcg1_w = (const float*)d_in[3];
  const float* fcg1_b = (const float*)d_in[4];
  const float* emb    = (const float*)d_in[5];
  const float* conv_w = (const float*)d_in[6];
  const float* conv_b = (const float*)d_in[7];
  const float* fcxt_w = (const float*)d_in[8];
  const float* fcxt_b = (const float*)d_in[9];
  const float* fc1_w  = (const float*)d_in[10];
  const float* fc1_b  = (const float*)d_in[11];
  const float* fc2_w  = (const float*)d_in[12];
  const float* fc2_b  = (const float*)d_in[13];
  const float* out_w  = (const float*)d_in[14];
  const float* out_b  = (const float*)d_in[15];
  const int* edge     = (const int*)d_in[16];
  const int* target   = (const int*)d_in[18];
  float* out = (float*)d_out;

  char* ws = (char*)d_ws;
  size_t off = 0;
  auto take = [&](size_t bytes) {
    void* p = ws + off;
    off += (bytes + 255) & ~(size_t)255;
    return p;
  };
  int*   deg    = (int*)  take((size_t)N_NODES * 4);
  float* dinv   = (float*)take((size_t)N_NODES * 4);
  int*   rowptr = (int*)  take((size_t)(N_NODES + 1) * 4);
  int*   bsum   = (int*)  take((size_t)SCAN_NBLK * 4);
  int*   cnt    = (int*)  take((size_t)N_NODES * 4);
  int*   csr    = (int*)  take((size_t)N_EDGES * 4);
  float* hA     = (float*)take((size_t)N_NODES * F_IN * 4);   // 46.8 MB
  float* hB     = (float*)take((size_t)N_NODES * F_IN * 4);   // 46.8 MB
  short* Bsw    = (short*)take((size_t)2 * BSW_HALF * 2);     // 123 KB
  int*   gkeys  = (int*)  take((size_t)BATCH * F_HID * 4);
  float* gbuf   = (float*)take((size_t)BATCH * F_HID * 4);
  float* Sg     = (float*)take((size_t)BATCH * NF * SK * 4);
  float* convo  = (float*)take((size_t)BATCH * NF * CONV_WO * 4);
  float* xc     = (float*)take((size_t)BATCH * 256 * 4);
  float* a1     = (float*)take((size_t)BATCH * 1024 * 4);
  float* a2     = (float*)take((size_t)BATCH * 512 * 4);
  // total ~120 MB (proven mapped in rounds 3-5)

  const int* esrc = edge;
  const int* edst = edge + N_EDGES;

  // CSR build (by destination)
  k_zero_i<<<(N_NODES + 255) / 256, 256, 0, stream>>>(deg, N_NODES);
  k_deg<<<(N_EDGES + 255) / 256, 256, 0, stream>>>(edst, deg);
  k_dinv<<<(N_NODES + 255) / 256, 256, 0, stream>>>(deg, dinv);
  k_scan1<<<SCAN_NBLK, 256, 0, stream>>>(deg, rowptr, bsum);
  k_scan2<<<1, 1024, 0, stream>>>(bsum);
  k_scan3<<<SCAN_NBLK, 256, 0, stream>>>(rowptr, bsum);
  k_zero_i<<<(N_NODES + 255) / 256, 256, 0, stream>>>(cnt, N_NODES);
  k_fillcsr<<<(N_EDGES + 255) / 256, 256, 0, stream>>>(esrc, edst, rowptr, cnt, csr);

  // SGConv via pull: p1 = dinv*x; p2 = dinv^2*(p1+sum); hA = dinv*(p2+sum)
  k_scale<<<(N_NODES * F_IN + 255) / 256, 256, 0, stream>>>(x, dinv, hA);
  k_pull<2><<<(N_NODES * 64 + 255) / 256, 256, 0, stream>>>(rowptr, csr, dinv, hA, hB);
  k_pull<1><<<(N_NODES * 64 + 255) / 256, 256, 0, stream>>>(rowptr, csr, dinv, hB, hA);

  // fused split-bf16 MFMA: h3 = leaky(hA @ sgc_w + sgc_b); gkeys = per-graph max
  k_bprep<<<(BSW_HALF + 255) / 256, 256, 0, stream>>>(sgc_w, Bsw);
  k_fill_i<<<(BATCH * F_HID + 255) / 256, 256, 0, stream>>>(gkeys, BATCH * F_HID, KEY_NEGMAX);
  k_gemm_max<<<(N_NODES + 63) / 64, 256, 0, stream>>>(hA, Bsw, sgc_b, gkeys);
  k_decode<<<(BATCH * F_HID + 255) / 256, 256, 0, stream>>>(gkeys, gbuf, BATCH * F_HID);

  // fcg1 + leaky -> xc[:, 0:128]
  dim3 g2((BATCH + 63) / 64, (OUT_DIMW + 63) / 64);
  k_gemm<2><<<g2, 256, 0, stream>>>(gbuf, fcg1_w, fcg1_b, xc, BATCH, OUT_DIMW, F_HID, 256, 0);

  // protein branch
  k_sbuild<<<BATCH, 256, 0, stream>>>(target, conv_w, Sg);
  k_conv<<<(BATCH * NF) / 32, 256, 0, stream>>>(Sg, emb, conv_b, convo);
  // xt = conv_flat @ fcxt_w + fcxt_b -> xc[:, 128:256]
  k_gemm<0><<<g2, 256, 0, stream>>>(convo, fcxt_w, fcxt_b, xc, BATCH, OUT_DIMW, CONV_FLAT, 256, OUT_DIMW);

  // head
  dim3 g3((BATCH + 63) / 64, (1024 + 63) / 64);
  k_gemm<1><<<g3, 256, 0, stream>>>(xc, fc1_w, fc1_b, a1, BATCH, 1024, 256, 1024, 0);
  dim3 g4((BATCH + 63) / 64, (512 + 63) / 64);
  k_gemm<1><<<g4, 256, 0, stream>>>(a1, fc2_w, fc2_b, a2, BATCH, 512, 1024, 512, 0);
  k_out<<<(BATCH * 64) / 256, 256, 0, stream>>>(a2, out_w, out_b, out);
}